// Round 3
// baseline (1186.909 us; speedup 1.0000x reference)
//
#include <hip/hip_runtime.h>
#include <cstdint>
#include <cstddef>

#define N_NODES 100000
#define N_EDGES 1600000

#define NBK   391                          // ceil(100000/256) buckets of 256 nodes
#define NPB   256                          // partition blocks
#define EPB   ((N_EDGES + NPB - 1) / NPB)  // 6250 edges per partition block
#define NSLOT (NBK * NPB)                  // 100096 (bucket-major: slot = b*NPB + bid)
#define NSB   ((NSLOT + 1023) / 1024)      // 98 scan blocks

// ---------------- CSR-lite build: bucket partition with private sub-regions ----------------

__global__ __launch_bounds__(256) void k_hist(const int* __restrict__ dst,
                                              int* __restrict__ gcnt, int E) {
    __shared__ int lh[NBK];
    int t = threadIdx.x, bid = blockIdx.x;
    for (int i = t; i < NBK; i += 256) lh[i] = 0;
    __syncthreads();
    int e0 = bid * EPB, e1 = min(E, e0 + EPB);
    for (int e = e0 + t; e < e1; e += 256) atomicAdd(&lh[dst[e] >> 8], 1);
    __syncthreads();
    for (int b = t; b < NBK; b += 256) gcnt[b * NPB + bid] = lh[b];
}

__global__ __launch_bounds__(1024) void k_scanA(int* __restrict__ g,
                                                int* __restrict__ bsum, int ntot) {
    __shared__ int s[1024];
    int t = threadIdx.x;
    int i = blockIdx.x * 1024 + t;
    int v = (i < ntot) ? g[i] : 0;
    s[t] = v;
    __syncthreads();
    for (int o = 1; o < 1024; o <<= 1) {
        int a = (t >= o) ? s[t - o] : 0;
        __syncthreads();
        s[t] += a;
        __syncthreads();
    }
    if (i < ntot) g[i] = s[t] - v;
    if (t == 1023) bsum[blockIdx.x] = s[1023];
}

__global__ __launch_bounds__(128) void k_scanB(int* __restrict__ bsum, int nb) {
    __shared__ int s[128];
    int t = threadIdx.x;
    int v = (t < nb) ? bsum[t] : 0;
    s[t] = v;
    __syncthreads();
    for (int o = 1; o < 128; o <<= 1) {
        int a = (t >= o) ? s[t - o] : 0;
        __syncthreads();
        s[t] += a;
        __syncthreads();
    }
    if (t < nb) bsum[t] = s[t] - v;
}

__global__ __launch_bounds__(1024) void k_scanC(int* __restrict__ g,
                                                const int* __restrict__ bsum, int ntot) {
    int i = blockIdx.x * 1024 + threadIdx.x;
    if (i < ntot) g[i] += bsum[blockIdx.x];
}

// pack src | (dstlocal)<<20 into per-(bucket,block) private regions; LDS cursors only
__global__ __launch_bounds__(256) void k_partition(const int* __restrict__ src,
                                                   const int* __restrict__ dst,
                                                   const int* __restrict__ base,
                                                   unsigned* __restrict__ ebuf, int E) {
    __shared__ int lcur[NBK];
    int t = threadIdx.x, bid = blockIdx.x;
    for (int b = t; b < NBK; b += 256) lcur[b] = base[b * NPB + bid];
    __syncthreads();
    int e0 = bid * EPB, e1 = min(E, e0 + EPB);
    for (int e = e0 + t; e < e1; e += 256) {
        int d = dst[e];
        int b = d >> 8;
        int p = atomicAdd(&lcur[b], 1);
        ebuf[p] = (unsigned)src[e] | ((unsigned)(d & 255) << 20);
    }
}

// per-node degree -> dinv, from bucketed edges (LDS histogram)
__global__ __launch_bounds__(256) void k_dinv_bucket(const int* __restrict__ base,
                                                     const unsigned* __restrict__ ebuf,
                                                     float* __restrict__ dinv, int n) {
    __shared__ int lc[256];
    int b = blockIdx.x, t = threadIdx.x;
    int start = base[b * NPB];
    int end = (b == NBK - 1) ? N_EDGES : base[(b + 1) * NPB];
    lc[t] = 0;
    __syncthreads();
    for (int e = start + t; e < end; e += 256) atomicAdd(&lc[(int)(ebuf[e] >> 20)], 1);
    __syncthreads();
    int node = b * 256 + t;
    if (node < n) dinv[node] = rsqrtf((float)lc[t] + 1.0f);
}

// ---------------- GEMM1: hw1 = x[M,256] @ w1[256,64] ----------------

__global__ __launch_bounds__(256) void k_gemm1(const float* __restrict__ x,
                                               const float* __restrict__ w,
                                               float* __restrict__ out, int M) {
    __shared__ float xs[64][64];   // [row][k]
    __shared__ float ws[64][64];   // [k][c]
    int t = threadIdx.x;
    int row0 = blockIdx.x * 64;
    int tx = t & 15;
    int ty = t >> 4;
    float acc[4][4] = {};

    for (int kb = 0; kb < 256; kb += 64) {
        __syncthreads();
        {
            int q = t & 15;
            int r = t >> 4;
#pragma unroll
            for (int p = 0; p < 4; p++) {
                int rr = r + p * 16;
                int grow = row0 + rr; if (grow >= M) grow = M - 1;
                float4 v = *(const float4*)&x[(size_t)grow * 256 + kb + q * 4];
                *(float4*)&xs[rr][q * 4] = v;
            }
#pragma unroll
            for (int p = 0; p < 4; p++) {
                int rr = r + p * 16;
                float4 v = *(const float4*)&w[(size_t)(kb + rr) * 64 + q * 4];
                *(float4*)&ws[rr][q * 4] = v;
            }
        }
        __syncthreads();
#pragma unroll 8
        for (int k = 0; k < 64; k++) {
            float4 b = *(const float4*)&ws[k][tx * 4];
#pragma unroll
            for (int i = 0; i < 4; i++) {
                float a = xs[ty * 4 + i][k];
                acc[i][0] += a * b.x;
                acc[i][1] += a * b.y;
                acc[i][2] += a * b.z;
                acc[i][3] += a * b.w;
            }
        }
    }
#pragma unroll
    for (int i = 0; i < 4; i++) {
        int grow = row0 + ty * 4 + i;
        if (grow < M) {
            float4 v;
            v.x = acc[i][0]; v.y = acc[i][1]; v.z = acc[i][2]; v.w = acc[i][3];
            *(float4*)&out[(size_t)grow * 64 + tx * 4] = v;
        }
    }
}

// ---------------- GEMM2: hw2 = h1[M,64] @ w2[64,32] ----------------

__global__ __launch_bounds__(256) void k_gemm2(const float* __restrict__ h,
                                               const float* __restrict__ w,
                                               float* __restrict__ out, int M) {
    __shared__ float hs[64][64];
    __shared__ float ws2[64][32];
    int t = threadIdx.x;
    int row0 = blockIdx.x * 64;
    {
        int q = t & 15, r = t >> 4;
#pragma unroll
        for (int p = 0; p < 4; p++) {
            int rr = r + p * 16;
            int grow = row0 + rr; if (grow >= M) grow = M - 1;
            *(float4*)&hs[rr][q * 4] = *(const float4*)&h[(size_t)grow * 64 + q * 4];
        }
#pragma unroll
        for (int p = 0; p < 2; p++) {
            int idx = t + p * 256;
            int kr = idx >> 3, cq = idx & 7;
            *(float4*)&ws2[kr][cq * 4] = *(const float4*)&w[(size_t)kr * 32 + cq * 4];
        }
    }
    __syncthreads();
    int tx = t & 7;
    int ty = t >> 3;
    float acc[2][4] = {};
#pragma unroll 8
    for (int k = 0; k < 64; k++) {
        float4 b = *(const float4*)&ws2[k][tx * 4];
        float a0 = hs[ty * 2 + 0][k];
        float a1 = hs[ty * 2 + 1][k];
        acc[0][0] += a0 * b.x; acc[0][1] += a0 * b.y; acc[0][2] += a0 * b.z; acc[0][3] += a0 * b.w;
        acc[1][0] += a1 * b.x; acc[1][1] += a1 * b.y; acc[1][2] += a1 * b.z; acc[1][3] += a1 * b.w;
    }
#pragma unroll
    for (int i = 0; i < 2; i++) {
        int grow = row0 + ty * 2 + i;
        if (grow < M) {
            float4 v;
            v.x = acc[i][0]; v.y = acc[i][1]; v.z = acc[i][2]; v.w = acc[i][3];
            *(float4*)&out[(size_t)grow * 32 + tx * 4] = v;
        }
    }
}

// ---------------- bucket aggregation: LDS-resident 256xD output tile ----------------
// h_out[node][c] = relu( sum_{e:dst=node} dinv[src]*dinv[node]*hw[src][c]
//                        + dinv[node]^2*hw[node][c] + bias[c] )

template <int D>
__global__ __launch_bounds__(256) void k_agg_bucket(const float* __restrict__ hw,
                                                    const float* __restrict__ dinv,
                                                    const int* __restrict__ base,
                                                    const unsigned* __restrict__ ebuf,
                                                    const float* __restrict__ bias,
                                                    float* __restrict__ hout, int n) {
    __shared__ float acc[256][D];
    __shared__ float dnl[256];
    __shared__ unsigned ew[1024];
    int b = blockIdx.x, t = threadIdx.x;
    int node0 = b * 256;
    int start = base[b * NPB];
    int end = (b == NBK - 1) ? N_EDGES : base[(b + 1) * NPB];

    {
        int node = node0 + t;
        dnl[t] = (node < n) ? dinv[node] : 0.0f;
    }
    __syncthreads();
    // init: self-loop term
#pragma unroll
    for (int it = 0; it < D / 4; ++it) {
        int idx = (it * 256 + t) * 4;
        int l = idx / D, c = idx % D;
        int node = node0 + l;
        float4 v = {0.f, 0.f, 0.f, 0.f};
        if (node < n) {
            v = *(const float4*)&hw[(size_t)node * D + c];
            float s = dnl[l] * dnl[l];
            v.x *= s; v.y *= s; v.z *= s; v.w *= s;
        }
        *(float4*)&acc[l][c] = v;
    }

    int w = t >> 6, lane = t & 63;
    for (int c0 = start; c0 < end; c0 += 1024) {
        int m = min(1024, end - c0);
        __syncthreads();
        for (int i = t; i < m; i += 256) ew[i] = ebuf[c0 + i];
        __syncthreads();
        if (D == 64) {
            int i = w;
            for (; i + 12 < m; i += 16) {
                unsigned u0 = ew[i], u1 = ew[i + 4], u2 = ew[i + 8], u3 = ew[i + 12];
                int s0 = u0 & 0xFFFFF, s1 = u1 & 0xFFFFF, s2 = u2 & 0xFFFFF, s3 = u3 & 0xFFFFF;
                int d0 = u0 >> 20, d1 = u1 >> 20, d2 = u2 >> 20, d3 = u3 >> 20;
                float v0 = hw[(size_t)s0 * 64 + lane];
                float v1 = hw[(size_t)s1 * 64 + lane];
                float v2 = hw[(size_t)s2 * 64 + lane];
                float v3 = hw[(size_t)s3 * 64 + lane];
                float w0 = dinv[s0] * dnl[d0];
                float w1 = dinv[s1] * dnl[d1];
                float w2 = dinv[s2] * dnl[d2];
                float w3 = dinv[s3] * dnl[d3];
                atomicAdd(&acc[d0][lane], w0 * v0);
                atomicAdd(&acc[d1][lane], w1 * v1);
                atomicAdd(&acc[d2][lane], w2 * v2);
                atomicAdd(&acc[d3][lane], w3 * v3);
            }
            for (; i < m; i += 4) {
                unsigned u = ew[i];
                int s = u & 0xFFFFF;
                int dl = u >> 20;
                atomicAdd(&acc[dl][lane], dinv[s] * dnl[dl] * hw[(size_t)s * 64 + lane]);
            }
        } else {
            int half = lane >> 5, c = lane & 31;
            int j = w * 2 + half;
            for (; j + 24 < m; j += 32) {
                unsigned u0 = ew[j], u1 = ew[j + 8], u2 = ew[j + 16], u3 = ew[j + 24];
                int s0 = u0 & 0xFFFFF, s1 = u1 & 0xFFFFF, s2 = u2 & 0xFFFFF, s3 = u3 & 0xFFFFF;
                int d0 = u0 >> 20, d1 = u1 >> 20, d2 = u2 >> 20, d3 = u3 >> 20;
                float v0 = hw[(size_t)s0 * 32 + c];
                float v1 = hw[(size_t)s1 * 32 + c];
                float v2 = hw[(size_t)s2 * 32 + c];
                float v3 = hw[(size_t)s3 * 32 + c];
                float w0 = dinv[s0] * dnl[d0];
                float w1 = dinv[s1] * dnl[d1];
                float w2 = dinv[s2] * dnl[d2];
                float w3 = dinv[s3] * dnl[d3];
                atomicAdd(&acc[d0][c], w0 * v0);
                atomicAdd(&acc[d1][c], w1 * v1);
                atomicAdd(&acc[d2][c], w2 * v2);
                atomicAdd(&acc[d3][c], w3 * v3);
            }
            for (; j < m; j += 8) {
                unsigned u = ew[j];
                int s = u & 0xFFFFF;
                int dl = u >> 20;
                atomicAdd(&acc[dl][c], dinv[s] * dnl[dl] * hw[(size_t)s * 32 + c]);
            }
        }
    }
    __syncthreads();
    // epilogue: bias + relu, coalesced store
#pragma unroll
    for (int it = 0; it < D / 4; ++it) {
        int idx = (it * 256 + t) * 4;
        int l = idx / D, c = idx % D;
        int node = node0 + l;
        if (node < n) {
            float4 a = *(float4*)&acc[l][c];
            float4 bb = *(const float4*)&bias[c];
            a.x = fmaxf(a.x + bb.x, 0.0f);
            a.y = fmaxf(a.y + bb.y, 0.0f);
            a.z = fmaxf(a.z + bb.z, 0.0f);
            a.w = fmaxf(a.w + bb.w, 0.0f);
            *(float4*)&hout[(size_t)node * D + c] = a;
        }
    }
}

// ---------------- final MLP head ----------------

__global__ __launch_bounds__(256) void k_final(const float* __restrict__ h2,
                                               const float* __restrict__ wf1,
                                               const float* __restrict__ bf1,
                                               const float* __restrict__ wf2,
                                               const float* __restrict__ bf2,
                                               float* __restrict__ out, int n) {
    __shared__ float W1[512];   // 32x16
    __shared__ float B1[16];
    __shared__ float W2[16];
    __shared__ float B2;
    int t = threadIdx.x;
    if (t < 256) { W1[t] = wf1[t]; W1[t + 256] = wf1[t + 256]; }
    if (t < 16) { B1[t] = bf1[t]; W2[t] = wf2[t]; }
    if (t == 0) B2 = bf2[0];
    __syncthreads();
    int i = blockIdx.x * 256 + t;
    if (i >= n) return;
    float h[32];
    const float4* hp = (const float4*)&h2[(size_t)i * 32];
#pragma unroll
    for (int q = 0; q < 8; q++) {
        float4 v = hp[q];
        h[q * 4 + 0] = v.x; h[q * 4 + 1] = v.y; h[q * 4 + 2] = v.z; h[q * 4 + 3] = v.w;
    }
    float o = B2;
#pragma unroll
    for (int jj = 0; jj < 16; jj++) {
        float s = B1[jj];
#pragma unroll
        for (int k = 0; k < 32; k++) s += h[k] * W1[k * 16 + jj];
        o += fmaxf(s, 0.0f) * W2[jj];
    }
    out[i] = o;
}

// ---------------- host ----------------

extern "C" void kernel_launch(void* const* d_in, const int* in_sizes, int n_in,
                              void* d_out, int out_size, void* d_ws, size_t ws_size,
                              hipStream_t stream) {
    const float* x   = (const float*)d_in[0];
    const int*   ei  = (const int*)d_in[1];
    const float* w1  = (const float*)d_in[2];
    const float* b1  = (const float*)d_in[3];
    const float* w2  = (const float*)d_in[4];
    const float* b2  = (const float*)d_in[5];
    const float* wf1 = (const float*)d_in[6];
    const float* bf1 = (const float*)d_in[7];
    const float* wf2 = (const float*)d_in[8];
    const float* bf2 = (const float*)d_in[9];

    const int n = N_NODES;
    const int E = N_EDGES;
    const int* srcp = ei;        // edge_index[0]
    const int* dstp = ei + E;    // edge_index[1]

    char* p = (char*)d_ws;
    auto take = [&](size_t bytes) {
        char* r = p;
        p += (bytes + 255) & ~(size_t)255;
        return r;
    };
    float*    dinv = (float*)take((size_t)n * 4);
    int*      gcnt = (int*)take((size_t)NSLOT * 4);
    int*      bsum = (int*)take(512);
    unsigned* ebuf = (unsigned*)take((size_t)E * 4);
    float*    hw1  = (float*)take((size_t)n * 64 * 4);
    float*    h1   = (float*)take((size_t)n * 64 * 4);
    float* hw2 = hw1;   // reuse after layer-1 aggregation consumed hw1
    float* h2  = h1;    // reuse after gemm2 consumed h1

    int gn = (n + 255) / 256;

    // bucket partition build
    k_hist<<<NPB, 256, 0, stream>>>(dstp, gcnt, E);
    k_scanA<<<NSB, 1024, 0, stream>>>(gcnt, bsum, NSLOT);
    k_scanB<<<1, 128, 0, stream>>>(bsum, NSB);
    k_scanC<<<NSB, 1024, 0, stream>>>(gcnt, bsum, NSLOT);
    k_partition<<<NPB, 256, 0, stream>>>(srcp, dstp, gcnt, ebuf, E);
    k_dinv_bucket<<<NBK, 256, 0, stream>>>(gcnt, ebuf, dinv, n);

    // GNN layers
    k_gemm1<<<(n + 63) / 64, 256, 0, stream>>>(x, w1, hw1, n);
    k_agg_bucket<64><<<NBK, 256, 0, stream>>>(hw1, dinv, gcnt, ebuf, b1, h1, n);
    k_gemm2<<<(n + 63) / 64, 256, 0, stream>>>(h1, w2, hw2, n);
    k_agg_bucket<32><<<NBK, 256, 0, stream>>>(hw2, dinv, gcnt, ebuf, b2, h2, n);
    k_final<<<gn, 256, 0, stream>>>(h2, wf1, bf1, wf2, bf2, (float*)d_out, n);
}

// Round 4
// 245.057 us; speedup vs baseline: 4.8434x; 4.8434x over previous
//
#include <hip/hip_runtime.h>
#include <cstdint>
#include <cstddef>

#define N_NODES 100000
#define N_EDGES 1600000

#define NBK   391                          // ceil(100000/256) buckets of 256 nodes
#define NPB   256                          // partition blocks
#define EPB   ((N_EDGES + NPB - 1) / NPB)  // 6250 edges per partition block
#define NSLOT (NBK * NPB)                  // 100096 (bucket-major: slot = b*NPB + bid)
#define NSB   ((NSLOT + 1023) / 1024)      // 98 scan blocks

__device__ __forceinline__ float b2f(unsigned short u) {
    return __uint_as_float(((unsigned)u) << 16);
}
__device__ __forceinline__ unsigned short f2b(float f) {
    unsigned x = __float_as_uint(f);
    return (unsigned short)((x + 0x7FFFu + ((x >> 16) & 1u)) >> 16);
}

// ---------------- build: bucket partition with private sub-regions ----------------

__global__ __launch_bounds__(256) void k_hist(const int* __restrict__ dst,
                                              int* __restrict__ gcnt, int E) {
    __shared__ int lh[NBK];
    int t = threadIdx.x, bid = blockIdx.x;
    for (int i = t; i < NBK; i += 256) lh[i] = 0;
    __syncthreads();
    int e0 = bid * EPB, e1 = min(E, e0 + EPB);
    for (int e = e0 + t; e < e1; e += 256) atomicAdd(&lh[dst[e] >> 8], 1);
    __syncthreads();
    for (int b = t; b < NBK; b += 256) gcnt[b * NPB + bid] = lh[b];
}

__global__ __launch_bounds__(1024) void k_scanA(int* __restrict__ g,
                                                int* __restrict__ bsum, int ntot) {
    __shared__ int s[1024];
    int t = threadIdx.x;
    int i = blockIdx.x * 1024 + t;
    int v = (i < ntot) ? g[i] : 0;
    s[t] = v;
    __syncthreads();
    for (int o = 1; o < 1024; o <<= 1) {
        int a = (t >= o) ? s[t - o] : 0;
        __syncthreads();
        s[t] += a;
        __syncthreads();
    }
    if (i < ntot) g[i] = s[t] - v;
    if (t == 1023) bsum[blockIdx.x] = s[1023];
}

__global__ __launch_bounds__(128) void k_scanB(int* __restrict__ bsum, int nb) {
    __shared__ int s[128];
    int t = threadIdx.x;
    int v = (t < nb) ? bsum[t] : 0;
    s[t] = v;
    __syncthreads();
    for (int o = 1; o < 128; o <<= 1) {
        int a = (t >= o) ? s[t - o] : 0;
        __syncthreads();
        s[t] += a;
        __syncthreads();
    }
    if (t < nb) bsum[t] = s[t] - v;
}

__global__ __launch_bounds__(1024) void k_scanC(int* __restrict__ g,
                                                const int* __restrict__ bsum, int ntot) {
    int i = blockIdx.x * 1024 + threadIdx.x;
    if (i < ntot) g[i] += bsum[blockIdx.x];
}

// pack src | (dstlocal)<<20 into per-(bucket,block) private regions; LDS cursors only
__global__ __launch_bounds__(256) void k_partition(const int* __restrict__ src,
                                                   const int* __restrict__ dst,
                                                   const int* __restrict__ base,
                                                   unsigned* __restrict__ ebuf, int E) {
    __shared__ int lcur[NBK];
    int t = threadIdx.x, bid = blockIdx.x;
    for (int b = t; b < NBK; b += 256) lcur[b] = base[b * NPB + bid];
    __syncthreads();
    int e0 = bid * EPB, e1 = min(E, e0 + EPB);
    for (int e = e0 + t; e < e1; e += 256) {
        int d = dst[e];
        int b = d >> 8;
        int p = atomicAdd(&lcur[b], 1);
        ebuf[p] = (unsigned)src[e] | ((unsigned)(d & 255) << 20);
    }
}

// one block per bucket: per-node count/scan/place entirely in LDS -> per-node CSR
__global__ __launch_bounds__(256) void k_bucket_csr(const int* __restrict__ base,
                                                    const unsigned* __restrict__ ebuf,
                                                    int* __restrict__ cnt,
                                                    float* __restrict__ dinv,
                                                    int* __restrict__ off,
                                                    int* __restrict__ es, int n) {
    __shared__ int lc[256];
    __shared__ int ss[256];
    __shared__ int lo[256];
    __shared__ int lcur[256];
    int b = blockIdx.x, t = threadIdx.x;
    int start = base[b * NPB];
    int end = (b == NBK - 1) ? N_EDGES : base[(b + 1) * NPB];
    lc[t] = 0;
    __syncthreads();
    for (int e = start + t; e < end; e += 256) atomicAdd(&lc[(int)(ebuf[e] >> 20)], 1);
    __syncthreads();
    int v = lc[t];
    ss[t] = v;
    __syncthreads();
    for (int o = 1; o < 256; o <<= 1) {
        int a = (t >= o) ? ss[t - o] : 0;
        __syncthreads();
        ss[t] += a;
        __syncthreads();
    }
    lo[t] = ss[t] - v;
    lcur[t] = 0;
    int node = b * 256 + t;
    if (node < n) {
        cnt[node] = v;
        dinv[node] = rsqrtf((float)v + 1.0f);
        off[node] = start + lo[t];
    }
    __syncthreads();
    for (int e = start + t; e < end; e += 256) {
        unsigned u = ebuf[e];
        int l = (int)(u >> 20);
        int p = atomicAdd(&lcur[l], 1);
        es[start + lo[l] + p] = (int)(u & 0xFFFFFu);
    }
}

// ---------------- GEMM1: hwb1 = bf16( x[M,256] @ w1[256,64] ) ----------------

__global__ __launch_bounds__(256) void k_gemm1(const float* __restrict__ x,
                                               const float* __restrict__ w,
                                               unsigned short* __restrict__ out, int M) {
    __shared__ float xs[64][64];   // [row][k]
    __shared__ float ws[64][64];   // [k][c]
    int t = threadIdx.x;
    int row0 = blockIdx.x * 64;
    int tx = t & 15;
    int ty = t >> 4;
    float acc[4][4] = {};

    for (int kb = 0; kb < 256; kb += 64) {
        __syncthreads();
        {
            int q = t & 15;
            int r = t >> 4;
#pragma unroll
            for (int p = 0; p < 4; p++) {
                int rr = r + p * 16;
                int grow = row0 + rr; if (grow >= M) grow = M - 1;
                float4 v = *(const float4*)&x[(size_t)grow * 256 + kb + q * 4];
                *(float4*)&xs[rr][q * 4] = v;
            }
#pragma unroll
            for (int p = 0; p < 4; p++) {
                int rr = r + p * 16;
                float4 v = *(const float4*)&w[(size_t)(kb + rr) * 64 + q * 4];
                *(float4*)&ws[rr][q * 4] = v;
            }
        }
        __syncthreads();
#pragma unroll 8
        for (int k = 0; k < 64; k++) {
            float4 b = *(const float4*)&ws[k][tx * 4];
#pragma unroll
            for (int i = 0; i < 4; i++) {
                float a = xs[ty * 4 + i][k];
                acc[i][0] += a * b.x;
                acc[i][1] += a * b.y;
                acc[i][2] += a * b.z;
                acc[i][3] += a * b.w;
            }
        }
    }
#pragma unroll
    for (int i = 0; i < 4; i++) {
        int grow = row0 + ty * 4 + i;
        if (grow < M) {
            ushort4 v;
            v.x = f2b(acc[i][0]); v.y = f2b(acc[i][1]);
            v.z = f2b(acc[i][2]); v.w = f2b(acc[i][3]);
            *(ushort4*)&out[(size_t)grow * 64 + tx * 4] = v;
        }
    }
}

// ---------------- GEMM2: hwb2 = bf16( h1[M,64] @ w2[64,32] ) ----------------

__global__ __launch_bounds__(256) void k_gemm2(const float* __restrict__ h,
                                               const float* __restrict__ w,
                                               unsigned short* __restrict__ out, int M) {
    __shared__ float hs[64][64];
    __shared__ float ws2[64][32];
    int t = threadIdx.x;
    int row0 = blockIdx.x * 64;
    {
        int q = t & 15, r = t >> 4;
#pragma unroll
        for (int p = 0; p < 4; p++) {
            int rr = r + p * 16;
            int grow = row0 + rr; if (grow >= M) grow = M - 1;
            *(float4*)&hs[rr][q * 4] = *(const float4*)&h[(size_t)grow * 64 + q * 4];
        }
#pragma unroll
        for (int p = 0; p < 2; p++) {
            int idx = t + p * 256;
            int kr = idx >> 3, cq = idx & 7;
            *(float4*)&ws2[kr][cq * 4] = *(const float4*)&w[(size_t)kr * 32 + cq * 4];
        }
    }
    __syncthreads();
    int tx = t & 7;
    int ty = t >> 3;
    float acc[2][4] = {};
#pragma unroll 8
    for (int k = 0; k < 64; k++) {
        float4 b = *(const float4*)&ws2[k][tx * 4];
        float a0 = hs[ty * 2 + 0][k];
        float a1 = hs[ty * 2 + 1][k];
        acc[0][0] += a0 * b.x; acc[0][1] += a0 * b.y; acc[0][2] += a0 * b.z; acc[0][3] += a0 * b.w;
        acc[1][0] += a1 * b.x; acc[1][1] += a1 * b.y; acc[1][2] += a1 * b.z; acc[1][3] += a1 * b.w;
    }
#pragma unroll
    for (int i = 0; i < 2; i++) {
        int grow = row0 + ty * 2 + i;
        if (grow < M) {
            ushort4 v;
            v.x = f2b(acc[i][0]); v.y = f2b(acc[i][1]);
            v.z = f2b(acc[i][2]); v.w = f2b(acc[i][3]);
            *(ushort4*)&out[(size_t)grow * 32 + tx * 4] = v;
        }
    }
}

// ---------------- aggregation: wave-per-node gather from bf16 operand ----------------

template <int D>
__global__ __launch_bounds__(256) void k_agg(const unsigned short* __restrict__ hwb,
                                             const float* __restrict__ dinv,
                                             const int* __restrict__ cnt,
                                             const int* __restrict__ off,
                                             const int* __restrict__ es,
                                             const float* __restrict__ bias,
                                             float* __restrict__ hout, int n) {
    int t = blockIdx.x * 256 + threadIdx.x;
    int node = t / D;
    int c = t % D;
    if (node >= n) return;
    float dn = dinv[node];
    float acc = dn * dn * b2f(hwb[(size_t)node * D + c]);   // self-loop term
    int base = off[node];
    int m = cnt[node];
    int j = 0;
    for (; j + 3 < m; j += 4) {
        int s0 = es[base + j];
        int s1 = es[base + j + 1];
        int s2 = es[base + j + 2];
        int s3 = es[base + j + 3];
        float w0 = dn * dinv[s0];
        float w1 = dn * dinv[s1];
        float w2 = dn * dinv[s2];
        float w3 = dn * dinv[s3];
        float v0 = b2f(hwb[(size_t)s0 * D + c]);
        float v1 = b2f(hwb[(size_t)s1 * D + c]);
        float v2 = b2f(hwb[(size_t)s2 * D + c]);
        float v3 = b2f(hwb[(size_t)s3 * D + c]);
        acc += w0 * v0;
        acc += w1 * v1;
        acc += w2 * v2;
        acc += w3 * v3;
    }
    for (; j < m; ++j) {
        int s0 = es[base + j];
        acc += dn * dinv[s0] * b2f(hwb[(size_t)s0 * D + c]);
    }
    acc += bias[c];
    hout[(size_t)node * D + c] = fmaxf(acc, 0.0f);
}

// ---------------- final MLP head ----------------

__global__ __launch_bounds__(256) void k_final(const float* __restrict__ h2,
                                               const float* __restrict__ wf1,
                                               const float* __restrict__ bf1,
                                               const float* __restrict__ wf2,
                                               const float* __restrict__ bf2,
                                               float* __restrict__ out, int n) {
    __shared__ float W1[512];   // 32x16
    __shared__ float B1[16];
    __shared__ float W2[16];
    __shared__ float B2;
    int t = threadIdx.x;
    if (t < 256) { W1[t] = wf1[t]; W1[t + 256] = wf1[t + 256]; }
    if (t < 16) { B1[t] = bf1[t]; W2[t] = wf2[t]; }
    if (t == 0) B2 = bf2[0];
    __syncthreads();
    int i = blockIdx.x * 256 + t;
    if (i >= n) return;
    float h[32];
    const float4* hp = (const float4*)&h2[(size_t)i * 32];
#pragma unroll
    for (int q = 0; q < 8; q++) {
        float4 v = hp[q];
        h[q * 4 + 0] = v.x; h[q * 4 + 1] = v.y; h[q * 4 + 2] = v.z; h[q * 4 + 3] = v.w;
    }
    float o = B2;
#pragma unroll
    for (int jj = 0; jj < 16; jj++) {
        float s = B1[jj];
#pragma unroll
        for (int k = 0; k < 32; k++) s += h[k] * W1[k * 16 + jj];
        o += fmaxf(s, 0.0f) * W2[jj];
    }
    out[i] = o;
}

// ---------------- host ----------------

extern "C" void kernel_launch(void* const* d_in, const int* in_sizes, int n_in,
                              void* d_out, int out_size, void* d_ws, size_t ws_size,
                              hipStream_t stream) {
    const float* x   = (const float*)d_in[0];
    const int*   ei  = (const int*)d_in[1];
    const float* w1  = (const float*)d_in[2];
    const float* b1  = (const float*)d_in[3];
    const float* w2  = (const float*)d_in[4];
    const float* b2  = (const float*)d_in[5];
    const float* wf1 = (const float*)d_in[6];
    const float* bf1 = (const float*)d_in[7];
    const float* wf2 = (const float*)d_in[8];
    const float* bf2 = (const float*)d_in[9];

    const int n = N_NODES;
    const int E = N_EDGES;
    const int* srcp = ei;        // edge_index[0]
    const int* dstp = ei + E;    // edge_index[1]

    char* p = (char*)d_ws;
    auto take = [&](size_t bytes) {
        char* r = p;
        p += (bytes + 255) & ~(size_t)255;
        return r;
    };
    float* dinv = (float*)take((size_t)n * 4);
    int*   cnt  = (int*)take((size_t)n * 4);
    int*   off  = (int*)take((size_t)n * 4);
    int*   gcnt = (int*)take((size_t)NSLOT * 4);
    int*   bsum = (int*)take(512);
    int*   es   = (int*)take((size_t)E * 4);
    unsigned short* hwb1 = (unsigned short*)take((size_t)n * 64 * 2);  // bf16; aliases ebuf
    float* h1   = (float*)take((size_t)n * 64 * 4);
    unsigned* ebuf = (unsigned*)hwb1;        // 6.4MB, consumed by k_bucket_csr before gemm1
    unsigned short* hwb2 = hwb1;             // reuse after agg1 consumed hwb1
    float* h2 = h1;                          // reuse after gemm2 consumed h1

    int gn = (n + 255) / 256;

    // build per-node CSR (bucketed two-phase, no global atomics)
    k_hist<<<NPB, 256, 0, stream>>>(dstp, gcnt, E);
    k_scanA<<<NSB, 1024, 0, stream>>>(gcnt, bsum, NSLOT);
    k_scanB<<<1, 128, 0, stream>>>(bsum, NSB);
    k_scanC<<<NSB, 1024, 0, stream>>>(gcnt, bsum, NSLOT);
    k_partition<<<NPB, 256, 0, stream>>>(srcp, dstp, gcnt, ebuf, E);
    k_bucket_csr<<<NBK, 256, 0, stream>>>(gcnt, ebuf, cnt, dinv, off, es, n);

    // GNN layers
    k_gemm1<<<(n + 63) / 64, 256, 0, stream>>>(x, w1, hwb1, n);
    k_agg<64><<<((size_t)n * 64 + 255) / 256, 256, 0, stream>>>(hwb1, dinv, cnt, off, es, b1, h1, n);
    k_gemm2<<<(n + 63) / 64, 256, 0, stream>>>(h1, w2, hwb2, n);
    k_agg<32><<<((size_t)n * 32 + 255) / 256, 256, 0, stream>>>(hwb2, dinv, cnt, off, es, b2, h2, n);
    k_final<<<gn, 256, 0, stream>>>(h2, wf1, bf1, wf2, bf2, (float*)d_out, n);
}

// Round 5
// 209.912 us; speedup vs baseline: 5.6543x; 1.1674x over previous
//
#include <hip/hip_runtime.h>
#include <cstdint>
#include <cstddef>

#define N_NODES 100000
#define N_EDGES 1600000

#define NBK   391                          // ceil(100000/256) buckets of 256 nodes
#define NPB   256                          // partition blocks
#define EPB   ((N_EDGES + NPB - 1) / NPB)  // 6250 edges per partition block
#define NSLOT (NBK * NPB)                  // 100096 (bucket-major: slot = b*NPB + bid)
#define NSB   ((NSLOT + 1023) / 1024)      // 98 scan blocks
#define ES_CAP (N_EDGES + NBK * 2048 + 64) // padded edge-list capacity

__device__ __forceinline__ float b2f(unsigned short u) {
    return __uint_as_float(((unsigned)u) << 16);
}
__device__ __forceinline__ unsigned short f2b(float f) {
    unsigned x = __float_as_uint(f);
    return (unsigned short)((x + 0x7FFFu + ((x >> 16) & 1u)) >> 16);
}

// ---------------- build: bucket partition with private sub-regions ----------------

__global__ __launch_bounds__(256) void k_hist(const int* __restrict__ dst,
                                              int* __restrict__ gcnt, int E) {
    __shared__ int lh[NBK];
    int t = threadIdx.x, bid = blockIdx.x;
    for (int i = t; i < NBK; i += 256) lh[i] = 0;
    __syncthreads();
    int e0 = bid * EPB, e1 = min(E, e0 + EPB);
    for (int e = e0 + t; e < e1; e += 256) atomicAdd(&lh[dst[e] >> 8], 1);
    __syncthreads();
    for (int b = t; b < NBK; b += 256) gcnt[b * NPB + bid] = lh[b];
}

__global__ __launch_bounds__(1024) void k_scanA(int* __restrict__ g,
                                                int* __restrict__ bsum, int ntot) {
    __shared__ int s[1024];
    int t = threadIdx.x;
    int i = blockIdx.x * 1024 + t;
    int v = (i < ntot) ? g[i] : 0;
    s[t] = v;
    __syncthreads();
    for (int o = 1; o < 1024; o <<= 1) {
        int a = (t >= o) ? s[t - o] : 0;
        __syncthreads();
        s[t] += a;
        __syncthreads();
    }
    if (i < ntot) g[i] = s[t] - v;
    if (t == 1023) bsum[blockIdx.x] = s[1023];
}

__global__ __launch_bounds__(128) void k_scanB(int* __restrict__ bsum, int nb) {
    __shared__ int s[128];
    int t = threadIdx.x;
    int v = (t < nb) ? bsum[t] : 0;
    s[t] = v;
    __syncthreads();
    for (int o = 1; o < 128; o <<= 1) {
        int a = (t >= o) ? s[t - o] : 0;
        __syncthreads();
        s[t] += a;
        __syncthreads();
    }
    if (t < nb) bsum[t] = s[t] - v;
}

__global__ __launch_bounds__(1024) void k_scanC(int* __restrict__ g,
                                                const int* __restrict__ bsum, int ntot) {
    int i = blockIdx.x * 1024 + threadIdx.x;
    if (i < ntot) g[i] += bsum[blockIdx.x];
}

// pack src | (dstlocal)<<20 into per-(bucket,block) private regions; LDS cursors only
__global__ __launch_bounds__(256) void k_partition(const int* __restrict__ src,
                                                   const int* __restrict__ dst,
                                                   const int* __restrict__ base,
                                                   unsigned* __restrict__ ebuf, int E) {
    __shared__ int lcur[NBK];
    int t = threadIdx.x, bid = blockIdx.x;
    for (int b = t; b < NBK; b += 256) lcur[b] = base[b * NPB + bid];
    __syncthreads();
    int e0 = bid * EPB, e1 = min(E, e0 + EPB);
    for (int e = e0 + t; e < e1; e += 256) {
        int d = dst[e];
        int b = d >> 8;
        int p = atomicAdd(&lcur[b], 1);
        ebuf[p] = (unsigned)src[e] | ((unsigned)(d & 255) << 20);
    }
}

// one block per bucket: per-node count/scan/place in LDS -> 8-padded per-node CSR.
// Padded slots get sentinel src = N_NODES (a zero row in hwb) so agg loops are tail-free
// and each node's list is 8-int (32B) aligned.
__global__ __launch_bounds__(256) void k_bucket_csr(const int* __restrict__ base,
                                                    const unsigned* __restrict__ ebuf,
                                                    int* __restrict__ cnt,
                                                    float* __restrict__ dinv,
                                                    int* __restrict__ off,
                                                    int* __restrict__ es, int n) {
    __shared__ int lc[256];
    __shared__ int ss[256];
    __shared__ int lo[256];
    __shared__ int lcur[256];
    int b = blockIdx.x, t = threadIdx.x;
    int rstart = base[b * NPB];
    int rend = (b == NBK - 1) ? N_EDGES : base[(b + 1) * NPB];
    int wstart = ((rstart + 7) & ~7) + b * 2048;   // 8-aligned private write region
    lc[t] = 0;
    __syncthreads();
    for (int e = rstart + t; e < rend; e += 256) atomicAdd(&lc[(int)(ebuf[e] >> 20)], 1);
    __syncthreads();
    int v = lc[t];               // real degree
    int vp = (v + 7) & ~7;       // padded to multiple of 8
    ss[t] = vp;
    __syncthreads();
    for (int o = 1; o < 256; o <<= 1) {
        int a = (t >= o) ? ss[t - o] : 0;
        __syncthreads();
        ss[t] += a;
        __syncthreads();
    }
    lo[t] = ss[t] - vp;          // padded exclusive offset within bucket
    lcur[t] = 0;
    int node = b * 256 + t;
    if (node < n) {
        cnt[node] = vp;          // padded count (loop bound)
        dinv[node] = rsqrtf((float)v + 1.0f);   // real degree + self-loop
        off[node] = wstart + lo[t];
    }
    __syncthreads();
    for (int e = rstart + t; e < rend; e += 256) {
        unsigned u = ebuf[e];
        int l = (int)(u >> 20);
        int p = atomicAdd(&lcur[l], 1);
        es[wstart + lo[l] + p] = (int)(u & 0xFFFFFu);
    }
    // fill pad slots [v, vp) of own node with sentinel (disjoint from placements)
    for (int q = v; q < vp; ++q) es[wstart + lo[t] + q] = N_NODES;
}

// zero the sentinel rows (row N) of both bf16 operand buffers
__global__ void k_zero_sent(unsigned short* __restrict__ hwb1,
                            unsigned short* __restrict__ hwb2) {
    int t = threadIdx.x;
    if (t < 64) hwb1[(size_t)N_NODES * 64 + t] = 0;
    else hwb2[(size_t)N_NODES * 32 + (t - 64)] = 0;
}

// ---------------- GEMM1: hwb1 = bf16( dinv[row] * (x[M,256] @ w1[256,64]) ) ----------------

__global__ __launch_bounds__(256) void k_gemm1(const float* __restrict__ x,
                                               const float* __restrict__ w,
                                               const float* __restrict__ dinv,
                                               unsigned short* __restrict__ out, int M) {
    __shared__ float xs[64][65];   // [k][row], padded
    __shared__ float ws[64][64];   // [k][c]
    int t = threadIdx.x;
    int row0 = blockIdx.x * 64;
    int tx = t & 15;
    int ty = t >> 4;
    float acc[4][4] = {};

    for (int kb = 0; kb < 256; kb += 64) {
        __syncthreads();
        {
            int q = t & 15;        // k-quad
            int r = t >> 4;        // 16 rows per pass
#pragma unroll
            for (int p = 0; p < 4; p++) {
                int rr = r + p * 16;
                int grow = row0 + rr; if (grow >= M) grow = M - 1;
                float4 v = *(const float4*)&x[(size_t)grow * 256 + kb + q * 4];
                xs[q * 4 + 0][rr] = v.x;
                xs[q * 4 + 1][rr] = v.y;
                xs[q * 4 + 2][rr] = v.z;
                xs[q * 4 + 3][rr] = v.w;
            }
#pragma unroll
            for (int p = 0; p < 4; p++) {
                int rr = r + p * 16;
                float4 v = *(const float4*)&w[(size_t)(kb + rr) * 64 + q * 4];
                *(float4*)&ws[rr][q * 4] = v;
            }
        }
        __syncthreads();
#pragma unroll 8
        for (int k = 0; k < 64; k++) {
            float4 a = *(const float4*)&xs[k][ty * 4];
            float4 b = *(const float4*)&ws[k][tx * 4];
            acc[0][0] += a.x * b.x; acc[0][1] += a.x * b.y; acc[0][2] += a.x * b.z; acc[0][3] += a.x * b.w;
            acc[1][0] += a.y * b.x; acc[1][1] += a.y * b.y; acc[1][2] += a.y * b.z; acc[1][3] += a.y * b.w;
            acc[2][0] += a.z * b.x; acc[2][1] += a.z * b.y; acc[2][2] += a.z * b.z; acc[2][3] += a.z * b.w;
            acc[3][0] += a.w * b.x; acc[3][1] += a.w * b.y; acc[3][2] += a.w * b.z; acc[3][3] += a.w * b.w;
        }
    }
#pragma unroll
    for (int i = 0; i < 4; i++) {
        int grow = row0 + ty * 4 + i;
        if (grow < M) {
            float s = dinv[grow];
            ushort4 v;
            v.x = f2b(acc[i][0] * s); v.y = f2b(acc[i][1] * s);
            v.z = f2b(acc[i][2] * s); v.w = f2b(acc[i][3] * s);
            *(ushort4*)&out[(size_t)grow * 64 + tx * 4] = v;
        }
    }
}

// ---------------- GEMM2: hwb2 = bf16( dinv[row] * (h1[M,64] @ w2[64,32]) ) ----------------

__global__ __launch_bounds__(256) void k_gemm2(const float* __restrict__ h,
                                               const float* __restrict__ w,
                                               const float* __restrict__ dinv,
                                               unsigned short* __restrict__ out, int M) {
    __shared__ float hs[64][64];
    __shared__ float ws2[64][32];
    int t = threadIdx.x;
    int row0 = blockIdx.x * 64;
    {
        int q = t & 15, r = t >> 4;
#pragma unroll
        for (int p = 0; p < 4; p++) {
            int rr = r + p * 16;
            int grow = row0 + rr; if (grow >= M) grow = M - 1;
            *(float4*)&hs[rr][q * 4] = *(const float4*)&h[(size_t)grow * 64 + q * 4];
        }
#pragma unroll
        for (int p = 0; p < 2; p++) {
            int idx = t + p * 256;
            int kr = idx >> 3, cq = idx & 7;
            *(float4*)&ws2[kr][cq * 4] = *(const float4*)&w[(size_t)kr * 32 + cq * 4];
        }
    }
    __syncthreads();
    int tx = t & 7;
    int ty = t >> 3;
    float acc[2][4] = {};
#pragma unroll 8
    for (int k = 0; k < 64; k++) {
        float4 b = *(const float4*)&ws2[k][tx * 4];
        float a0 = hs[ty * 2 + 0][k];
        float a1 = hs[ty * 2 + 1][k];
        acc[0][0] += a0 * b.x; acc[0][1] += a0 * b.y; acc[0][2] += a0 * b.z; acc[0][3] += a0 * b.w;
        acc[1][0] += a1 * b.x; acc[1][1] += a1 * b.y; acc[1][2] += a1 * b.z; acc[1][3] += a1 * b.w;
    }
#pragma unroll
    for (int i = 0; i < 2; i++) {
        int grow = row0 + ty * 2 + i;
        if (grow < M) {
            float s = dinv[grow];
            ushort4 v;
            v.x = f2b(acc[i][0] * s); v.y = f2b(acc[i][1] * s);
            v.z = f2b(acc[i][2] * s); v.w = f2b(acc[i][3] * s);
            *(ushort4*)&out[(size_t)grow * 32 + tx * 4] = v;
        }
    }
}

// ---------------- agg layer 1: wave-per-node, pre-scaled bf16 operand ----------------
// h1[node][c] = relu( dinv[node] * ( hwb[node][c] + sum_edges hwb[src][c] ) + b1[c] )

__global__ __launch_bounds__(256) void k_agg1(const unsigned short* __restrict__ hwb,
                                              const float* __restrict__ dinv,
                                              const int* __restrict__ cnt,
                                              const int* __restrict__ off,
                                              const int* __restrict__ es,
                                              const float* __restrict__ bias,
                                              float* __restrict__ hout) {
    int t = blockIdx.x * 256 + threadIdx.x;
    int node = t >> 6;
    int c = t & 63;
    float dn = dinv[node];
    float acc0 = b2f(hwb[(size_t)node * 64 + c]);   // self-loop (pre-scaled)
    float acc1 = 0.0f;
    const int* ep = es + off[node];                 // 32B-aligned, length multiple of 8
    int mp = cnt[node];
    for (int j = 0; j < mp; j += 8) {
        int4 e0 = *(const int4*)&ep[j];
        int4 e1 = *(const int4*)&ep[j + 4];
        float v0 = b2f(hwb[(size_t)e0.x * 64 + c]);
        float v1 = b2f(hwb[(size_t)e0.y * 64 + c]);
        float v2 = b2f(hwb[(size_t)e0.z * 64 + c]);
        float v3 = b2f(hwb[(size_t)e0.w * 64 + c]);
        float v4 = b2f(hwb[(size_t)e1.x * 64 + c]);
        float v5 = b2f(hwb[(size_t)e1.y * 64 + c]);
        float v6 = b2f(hwb[(size_t)e1.z * 64 + c]);
        float v7 = b2f(hwb[(size_t)e1.w * 64 + c]);
        acc0 += (v0 + v1) + (v2 + v3);
        acc1 += (v4 + v5) + (v6 + v7);
    }
    float acc = acc0 + acc1;
    hout[(size_t)node * 64 + c] = fmaxf(fmaf(dn, acc, bias[c]), 0.0f);
}

// ---------------- agg layer 2 + fused MLP head ----------------
// per block: 8 nodes x 32 feats; h2 kept in LDS; out[node] = mlp(h2[node])

__global__ __launch_bounds__(256) void k_agg2_mlp(const unsigned short* __restrict__ hwb,
                                                  const float* __restrict__ dinv,
                                                  const int* __restrict__ cnt,
                                                  const int* __restrict__ off,
                                                  const int* __restrict__ es,
                                                  const float* __restrict__ bias2,
                                                  const float* __restrict__ wf1,
                                                  const float* __restrict__ bf1,
                                                  const float* __restrict__ wf2,
                                                  const float* __restrict__ bf2,
                                                  float* __restrict__ out) {
    __shared__ float hs[8][33];
    __shared__ float W1[512];
    __shared__ float B1[16];
    __shared__ float W2[16];
    int t = threadIdx.x;
    W1[t] = wf1[t];
    W1[t + 256] = wf1[t + 256];
    if (t < 16) { B1[t] = bf1[t]; W2[t] = wf2[t]; }

    int node0 = blockIdx.x * 8;
    int nl = t >> 5;            // local node 0..7
    int c = t & 31;
    int node = node0 + nl;
    float dn = dinv[node];
    float acc0 = b2f(hwb[(size_t)node * 32 + c]);
    float acc1 = 0.0f;
    const int* ep = es + off[node];
    int mp = cnt[node];
    for (int j = 0; j < mp; j += 8) {
        int4 e0 = *(const int4*)&ep[j];
        int4 e1 = *(const int4*)&ep[j + 4];
        float v0 = b2f(hwb[(size_t)e0.x * 32 + c]);
        float v1 = b2f(hwb[(size_t)e0.y * 32 + c]);
        float v2 = b2f(hwb[(size_t)e0.z * 32 + c]);
        float v3 = b2f(hwb[(size_t)e0.w * 32 + c]);
        float v4 = b2f(hwb[(size_t)e1.x * 32 + c]);
        float v5 = b2f(hwb[(size_t)e1.y * 32 + c]);
        float v6 = b2f(hwb[(size_t)e1.z * 32 + c]);
        float v7 = b2f(hwb[(size_t)e1.w * 32 + c]);
        acc0 += (v0 + v1) + (v2 + v3);
        acc1 += (v4 + v5) + (v6 + v7);
    }
    hs[nl][c] = fmaxf(fmaf(dn, acc0 + acc1, bias2[c]), 0.0f);
    __syncthreads();
    if (t < 128) {
        int nn = t >> 4, jj = t & 15;
        float s = B1[jj];
#pragma unroll
        for (int k = 0; k < 32; ++k) s += hs[nn][k] * W1[k * 16 + jj];
        float p = fmaxf(s, 0.0f) * W2[jj];
        p += __shfl_xor(p, 1);
        p += __shfl_xor(p, 2);
        p += __shfl_xor(p, 4);
        p += __shfl_xor(p, 8);
        if (jj == 0) out[node0 + nn] = p + bf2[0];
    }
}

// ---------------- host ----------------

extern "C" void kernel_launch(void* const* d_in, const int* in_sizes, int n_in,
                              void* d_out, int out_size, void* d_ws, size_t ws_size,
                              hipStream_t stream) {
    const float* x   = (const float*)d_in[0];
    const int*   ei  = (const int*)d_in[1];
    const float* w1  = (const float*)d_in[2];
    const float* b1  = (const float*)d_in[3];
    const float* w2  = (const float*)d_in[4];
    const float* b2  = (const float*)d_in[5];
    const float* wf1 = (const float*)d_in[6];
    const float* bf1 = (const float*)d_in[7];
    const float* wf2 = (const float*)d_in[8];
    const float* bf2 = (const float*)d_in[9];

    const int n = N_NODES;
    const int E = N_EDGES;
    const int* srcp = ei;        // edge_index[0]
    const int* dstp = ei + E;    // edge_index[1]

    char* p = (char*)d_ws;
    auto take = [&](size_t bytes) {
        char* r = p;
        p += (bytes + 255) & ~(size_t)255;
        return r;
    };
    float* dinv = (float*)take((size_t)n * 4);
    int*   cnt  = (int*)take((size_t)n * 4);
    int*   off  = (int*)take((size_t)n * 4);
    int*   gcnt = (int*)take((size_t)NSLOT * 4);
    int*   bsum = (int*)take(512);
    int*   es   = (int*)take((size_t)ES_CAP * 4);
    unsigned short* hwb1 = (unsigned short*)take((size_t)(n + 1) * 64 * 2);  // aliases ebuf
    unsigned short* hwb2 = (unsigned short*)take((size_t)(n + 1) * 32 * 2);
    float* h1   = (float*)take((size_t)n * 64 * 4);
    unsigned* ebuf = (unsigned*)hwb1;   // 6.4MB, consumed by k_bucket_csr before gemm1

    // build per-node padded CSR (bucketed two-phase, no global atomics)
    k_zero_sent<<<1, 96, 0, stream>>>(hwb1, hwb2);
    k_hist<<<NPB, 256, 0, stream>>>(dstp, gcnt, E);
    k_scanA<<<NSB, 1024, 0, stream>>>(gcnt, bsum, NSLOT);
    k_scanB<<<1, 128, 0, stream>>>(bsum, NSB);
    k_scanC<<<NSB, 1024, 0, stream>>>(gcnt, bsum, NSLOT);
    k_partition<<<NPB, 256, 0, stream>>>(srcp, dstp, gcnt, ebuf, E);
    k_bucket_csr<<<NBK, 256, 0, stream>>>(gcnt, ebuf, cnt, dinv, off, es, n);

    // GNN layers
    k_gemm1<<<(n + 63) / 64, 256, 0, stream>>>(x, w1, dinv, hwb1, n);
    k_agg1<<<(n * 64) / 256, 256, 0, stream>>>(hwb1, dinv, cnt, off, es, b1, h1);
    k_gemm2<<<(n + 63) / 64, 256, 0, stream>>>(h1, w2, dinv, hwb2, n);
    k_agg2_mlp<<<n / 8, 256, 0, stream>>>(hwb2, dinv, cnt, off, es, b2,
                                          wf1, bf1, wf2, bf2, (float*)d_out);
}

// Round 6
// 178.816 us; speedup vs baseline: 6.6376x; 1.1739x over previous
//
#include <hip/hip_runtime.h>
#include <cstdint>
#include <cstddef>

#define N_NODES 100000
#define N_EDGES 1600000

#define NBK   391                          // ceil(100000/256) buckets of 256 nodes
#define NPB   256                          // partition blocks
#define EPB   ((N_EDGES + NPB - 1) / NPB)  // 6250 edges per partition block
#define NSLOT (NBK * NPB)                  // 100096 (bucket-major: slot = b*NPB + bid)
#define NSB   ((NSLOT + 1023) / 1024)      // 98 scan blocks
#define ES_CAP (N_EDGES + NBK * 2048 + 64) // padded edge-list capacity

typedef __attribute__((ext_vector_type(8))) short bf16x8;
typedef __attribute__((ext_vector_type(4))) float f32x4;

__device__ __forceinline__ float b2f(unsigned short u) {
    return __uint_as_float(((unsigned)u) << 16);
}
__device__ __forceinline__ unsigned short f2b(float f) {
    unsigned x = __float_as_uint(f);
    return (unsigned short)((x + 0x7FFFu + ((x >> 16) & 1u)) >> 16);
}

// split f32 -> bf16 hi (trunc) + bf16 lo (trunc of exact residual)
__device__ __forceinline__ void split8(const float4& a0, const float4& a1,
                                       bf16x8& hi, bf16x8& lo) {
    float f[8] = {a0.x, a0.y, a0.z, a0.w, a1.x, a1.y, a1.z, a1.w};
#pragma unroll
    for (int j = 0; j < 8; ++j) {
        unsigned u = __float_as_uint(f[j]);
        hi[j] = (short)(u >> 16);
        float l = f[j] - __uint_as_float(u & 0xFFFF0000u);   // exact
        lo[j] = (short)(__float_as_uint(l) >> 16);
    }
}

// ---------------- build: bucket partition with private sub-regions ----------------

__global__ __launch_bounds__(256) void k_hist(const int* __restrict__ dst,
                                              int* __restrict__ gcnt, int E) {
    __shared__ int lh[NBK];
    int t = threadIdx.x, bid = blockIdx.x;
    for (int i = t; i < NBK; i += 256) lh[i] = 0;
    __syncthreads();
    int e0 = bid * EPB, e1 = min(E, e0 + EPB);
    for (int e = e0 + t; e < e1; e += 256) atomicAdd(&lh[dst[e] >> 8], 1);
    __syncthreads();
    for (int b = t; b < NBK; b += 256) gcnt[b * NPB + bid] = lh[b];
}

__global__ __launch_bounds__(1024) void k_scanA(int* __restrict__ g,
                                                int* __restrict__ bsum, int ntot) {
    __shared__ int s[1024];
    int t = threadIdx.x;
    int i = blockIdx.x * 1024 + t;
    int v = (i < ntot) ? g[i] : 0;
    s[t] = v;
    __syncthreads();
    for (int o = 1; o < 1024; o <<= 1) {
        int a = (t >= o) ? s[t - o] : 0;
        __syncthreads();
        s[t] += a;
        __syncthreads();
    }
    if (i < ntot) g[i] = s[t] - v;
    if (t == 1023) bsum[blockIdx.x] = s[1023];
}

__global__ __launch_bounds__(128) void k_scanB(int* __restrict__ bsum, int nb) {
    __shared__ int s[128];
    int t = threadIdx.x;
    int v = (t < nb) ? bsum[t] : 0;
    s[t] = v;
    __syncthreads();
    for (int o = 1; o < 128; o <<= 1) {
        int a = (t >= o) ? s[t - o] : 0;
        __syncthreads();
        s[t] += a;
        __syncthreads();
    }
    if (t < nb) bsum[t] = s[t] - v;
}

__global__ __launch_bounds__(1024) void k_scanC(int* __restrict__ g,
                                                const int* __restrict__ bsum, int ntot) {
    int i = blockIdx.x * 1024 + threadIdx.x;
    if (i < ntot) g[i] += bsum[blockIdx.x];
}

__global__ __launch_bounds__(256) void k_partition(const int* __restrict__ src,
                                                   const int* __restrict__ dst,
                                                   const int* __restrict__ base,
                                                   unsigned* __restrict__ ebuf, int E) {
    __shared__ int lcur[NBK];
    int t = threadIdx.x, bid = blockIdx.x;
    for (int b = t; b < NBK; b += 256) lcur[b] = base[b * NPB + bid];
    __syncthreads();
    int e0 = bid * EPB, e1 = min(E, e0 + EPB);
    for (int e = e0 + t; e < e1; e += 256) {
        int d = dst[e];
        int b = d >> 8;
        int p = atomicAdd(&lcur[b], 1);
        ebuf[p] = (unsigned)src[e] | ((unsigned)(d & 255) << 20);
    }
}

// one block per bucket: per-node count/scan/place in LDS -> 8-padded per-node CSR.
__global__ __launch_bounds__(256) void k_bucket_csr(const int* __restrict__ base,
                                                    const unsigned* __restrict__ ebuf,
                                                    int* __restrict__ cnt,
                                                    float* __restrict__ dinv,
                                                    int* __restrict__ off,
                                                    int* __restrict__ es, int n) {
    __shared__ int lc[256];
    __shared__ int ss[256];
    __shared__ int lo[256];
    __shared__ int lcur[256];
    int b = blockIdx.x, t = threadIdx.x;
    int rstart = base[b * NPB];
    int rend = (b == NBK - 1) ? N_EDGES : base[(b + 1) * NPB];
    int wstart = ((rstart + 7) & ~7) + b * 2048;   // 8-aligned private write region
    lc[t] = 0;
    __syncthreads();
    for (int e = rstart + t; e < rend; e += 256) atomicAdd(&lc[(int)(ebuf[e] >> 20)], 1);
    __syncthreads();
    int v = lc[t];               // real degree
    int vp = (v + 7) & ~7;       // padded to multiple of 8
    ss[t] = vp;
    __syncthreads();
    for (int o = 1; o < 256; o <<= 1) {
        int a = (t >= o) ? ss[t - o] : 0;
        __syncthreads();
        ss[t] += a;
        __syncthreads();
    }
    lo[t] = ss[t] - vp;
    lcur[t] = 0;
    int node = b * 256 + t;
    if (node < n) {
        cnt[node] = vp;
        dinv[node] = rsqrtf((float)v + 1.0f);
        off[node] = wstart + lo[t];
    }
    __syncthreads();
    for (int e = rstart + t; e < rend; e += 256) {
        unsigned u = ebuf[e];
        int l = (int)(u >> 20);
        int p = atomicAdd(&lcur[l], 1);
        es[wstart + lo[l] + p] = (int)(u & 0xFFFFFu);
    }
    for (int q = v; q < vp; ++q) es[wstart + lo[t] + q] = N_NODES;
}

// zero the sentinel rows (row N) of both bf16 operand buffers
__global__ void k_zero_sent(unsigned short* __restrict__ hwb1,
                            unsigned short* __restrict__ hwb2) {
    int t = threadIdx.x;
    if (t < 64) hwb1[(size_t)N_NODES * 64 + t] = 0;
    else hwb2[(size_t)N_NODES * 32 + (t - 64)] = 0;
}

// ---------------- GEMM1 (MFMA hi/lo): hwb1 = bf16( dinv * (x[M,256] @ w1[256,64]) ) ----
// block = 256 thr = 4 waves; tile 64 rows x 64 cols; K=256 fully LDS-resident (w only).
// A-frag loaded global->reg: lane l holds rows row0w+(l&15), k = kf*32+(l>>4)*8+j.
// B in LDS: [kgrp][col][8] bf16, kgrp = k>>3.

__global__ __launch_bounds__(256) void k_gemm1_mfma(const float* __restrict__ x,
                                                    const float* __restrict__ w,
                                                    const float* __restrict__ dinv,
                                                    unsigned short* __restrict__ out, int M) {
    __shared__ unsigned short Bhi[32 * 64 * 8];   // 32 KB
    __shared__ unsigned short Blo[32 * 64 * 8];   // 32 KB
    int t = threadIdx.x;
    int wave = t >> 6, lane = t & 63;

    // stage w1 -> LDS bf16 hi/lo in B-frag layout
    {
        int c = t & 63;          // col
        int kg0 = t >> 6;        // 0..3
#pragma unroll
        for (int i = 0; i < 8; ++i) {
            int kgrp = kg0 + i * 4;          // 0..31
            bf16x8 h8, l8;
#pragma unroll
            for (int j = 0; j < 8; ++j) {
                float f = w[(size_t)(kgrp * 8 + j) * 64 + c];
                unsigned u = __float_as_uint(f);
                h8[j] = (short)(u >> 16);
                float l = f - __uint_as_float(u & 0xFFFF0000u);
                l8[j] = (short)(__float_as_uint(l) >> 16);
            }
            *(bf16x8*)&Bhi[(kgrp * 64 + c) * 8] = h8;
            *(bf16x8*)&Blo[(kgrp * 64 + c) * 8] = l8;
        }
    }
    __syncthreads();

    int row0w = blockIdx.x * 64 + wave * 16;
    int r = row0w + (lane & 15); if (r >= M) r = M - 1;
    const float* xr = x + (size_t)r * 256 + (lane >> 4) * 8;

    f32x4 acc[4] = {{0.f,0.f,0.f,0.f},{0.f,0.f,0.f,0.f},{0.f,0.f,0.f,0.f},{0.f,0.f,0.f,0.f}};

#pragma unroll
    for (int kf = 0; kf < 8; ++kf) {
        float4 a0 = *(const float4*)(xr + kf * 32);
        float4 a1 = *(const float4*)(xr + kf * 32 + 4);
        bf16x8 ahi, alo;
        split8(a0, a1, ahi, alo);
        int kgrpR = kf * 4 + (lane >> 4);
#pragma unroll
        for (int cf = 0; cf < 4; ++cf) {
            bf16x8 bhi = *(const bf16x8*)&Bhi[(kgrpR * 64 + cf * 16 + (lane & 15)) * 8];
            bf16x8 blo = *(const bf16x8*)&Blo[(kgrpR * 64 + cf * 16 + (lane & 15)) * 8];
            acc[cf] = __builtin_amdgcn_mfma_f32_16x16x32_bf16(ahi, bhi, acc[cf], 0, 0, 0);
            acc[cf] = __builtin_amdgcn_mfma_f32_16x16x32_bf16(ahi, blo, acc[cf], 0, 0, 0);
            acc[cf] = __builtin_amdgcn_mfma_f32_16x16x32_bf16(alo, bhi, acc[cf], 0, 0, 0);
        }
    }

    // epilogue: C row = row0w + (lane>>4)*4 + j, col = cf*16 + (lane&15)
#pragma unroll
    for (int j = 0; j < 4; ++j) {
        int rr = row0w + (lane >> 4) * 4 + j;
        if (rr < M) {
            float s = dinv[rr];
#pragma unroll
            for (int cf = 0; cf < 4; ++cf)
                out[(size_t)rr * 64 + cf * 16 + (lane & 15)] = f2b(acc[cf][j] * s);
        }
    }
}

// ---------------- GEMM2 (MFMA hi/lo): hwb2 = bf16( dinv * (h1[M,64] @ w2[64,32]) ) -----

__global__ __launch_bounds__(256) void k_gemm2_mfma(const float* __restrict__ h,
                                                    const float* __restrict__ w,
                                                    const float* __restrict__ dinv,
                                                    unsigned short* __restrict__ out, int M) {
    __shared__ unsigned short Bhi[8 * 32 * 8];   // 4 KB
    __shared__ unsigned short Blo[8 * 32 * 8];   // 4 KB
    int t = threadIdx.x;
    int wave = t >> 6, lane = t & 63;

    {
        int c = t & 31;          // col
        int kg = t >> 5;         // 0..7
        bf16x8 h8, l8;
#pragma unroll
        for (int j = 0; j < 8; ++j) {
            float f = w[(size_t)(kg * 8 + j) * 32 + c];
            unsigned u = __float_as_uint(f);
            h8[j] = (short)(u >> 16);
            float l = f - __uint_as_float(u & 0xFFFF0000u);
            l8[j] = (short)(__float_as_uint(l) >> 16);
        }
        *(bf16x8*)&Bhi[(kg * 32 + c) * 8] = h8;
        *(bf16x8*)&Blo[(kg * 32 + c) * 8] = l8;
    }
    __syncthreads();

    int row0w = blockIdx.x * 64 + wave * 16;
    int r = row0w + (lane & 15); if (r >= M) r = M - 1;
    const float* xr = h + (size_t)r * 64 + (lane >> 4) * 8;

    f32x4 acc[2] = {{0.f,0.f,0.f,0.f},{0.f,0.f,0.f,0.f}};

#pragma unroll
    for (int kf = 0; kf < 2; ++kf) {
        float4 a0 = *(const float4*)(xr + kf * 32);
        float4 a1 = *(const float4*)(xr + kf * 32 + 4);
        bf16x8 ahi, alo;
        split8(a0, a1, ahi, alo);
        int kgrpR = kf * 4 + (lane >> 4);
#pragma unroll
        for (int cf = 0; cf < 2; ++cf) {
            bf16x8 bhi = *(const bf16x8*)&Bhi[(kgrpR * 32 + cf * 16 + (lane & 15)) * 8];
            bf16x8 blo = *(const bf16x8*)&Blo[(kgrpR * 32 + cf * 16 + (lane & 15)) * 8];
            acc[cf] = __builtin_amdgcn_mfma_f32_16x16x32_bf16(ahi, bhi, acc[cf], 0, 0, 0);
            acc[cf] = __builtin_amdgcn_mfma_f32_16x16x32_bf16(ahi, blo, acc[cf], 0, 0, 0);
            acc[cf] = __builtin_amdgcn_mfma_f32_16x16x32_bf16(alo, bhi, acc[cf], 0, 0, 0);
        }
    }

#pragma unroll
    for (int j = 0; j < 4; ++j) {
        int rr = row0w + (lane >> 4) * 4 + j;
        if (rr < M) {
            float s = dinv[rr];
#pragma unroll
            for (int cf = 0; cf < 2; ++cf)
                out[(size_t)rr * 32 + cf * 16 + (lane & 15)] = f2b(acc[cf][j] * s);
        }
    }
}

// ---------------- agg layer 1: wave-per-node, pre-scaled bf16 operand ----------------

__global__ __launch_bounds__(256) void k_agg1(const unsigned short* __restrict__ hwb,
                                              const float* __restrict__ dinv,
                                              const int* __restrict__ cnt,
                                              const int* __restrict__ off,
                                              const int* __restrict__ es,
                                              const float* __restrict__ bias,
                                              float* __restrict__ hout) {
    int t = blockIdx.x * 256 + threadIdx.x;
    int node = t >> 6;
    int c = t & 63;
    float dn = dinv[node];
    float acc0 = b2f(hwb[(size_t)node * 64 + c]);   // self-loop (pre-scaled)
    float acc1 = 0.0f;
    const int* ep = es + off[node];
    int mp = cnt[node];
    for (int j = 0; j < mp; j += 8) {
        int4 e0 = *(const int4*)&ep[j];
        int4 e1 = *(const int4*)&ep[j + 4];
        float v0 = b2f(hwb[(size_t)e0.x * 64 + c]);
        float v1 = b2f(hwb[(size_t)e0.y * 64 + c]);
        float v2 = b2f(hwb[(size_t)e0.z * 64 + c]);
        float v3 = b2f(hwb[(size_t)e0.w * 64 + c]);
        float v4 = b2f(hwb[(size_t)e1.x * 64 + c]);
        float v5 = b2f(hwb[(size_t)e1.y * 64 + c]);
        float v6 = b2f(hwb[(size_t)e1.z * 64 + c]);
        float v7 = b2f(hwb[(size_t)e1.w * 64 + c]);
        acc0 += (v0 + v1) + (v2 + v3);
        acc1 += (v4 + v5) + (v6 + v7);
    }
    float acc = acc0 + acc1;
    hout[(size_t)node * 64 + c] = fmaxf(fmaf(dn, acc, bias[c]), 0.0f);
}

// ---------------- agg layer 2 + fused MLP head ----------------

__global__ __launch_bounds__(256) void k_agg2_mlp(const unsigned short* __restrict__ hwb,
                                                  const float* __restrict__ dinv,
                                                  const int* __restrict__ cnt,
                                                  const int* __restrict__ off,
                                                  const int* __restrict__ es,
                                                  const float* __restrict__ bias2,
                                                  const float* __restrict__ wf1,
                                                  const float* __restrict__ bf1,
                                                  const float* __restrict__ wf2,
                                                  const float* __restrict__ bf2,
                                                  float* __restrict__ out) {
    __shared__ float hs[8][33];
    __shared__ float W1[512];
    __shared__ float B1[16];
    __shared__ float W2[16];
    int t = threadIdx.x;
    W1[t] = wf1[t];
    W1[t + 256] = wf1[t + 256];
    if (t < 16) { B1[t] = bf1[t]; W2[t] = wf2[t]; }

    int node0 = blockIdx.x * 8;
    int nl = t >> 5;
    int c = t & 31;
    int node = node0 + nl;
    float dn = dinv[node];
    float acc0 = b2f(hwb[(size_t)node * 32 + c]);
    float acc1 = 0.0f;
    const int* ep = es + off[node];
    int mp = cnt[node];
    for (int j = 0; j < mp; j += 8) {
        int4 e0 = *(const int4*)&ep[j];
        int4 e1 = *(const int4*)&ep[j + 4];
        float v0 = b2f(hwb[(size_t)e0.x * 32 + c]);
        float v1 = b2f(hwb[(size_t)e0.y * 32 + c]);
        float v2 = b2f(hwb[(size_t)e0.z * 32 + c]);
        float v3 = b2f(hwb[(size_t)e0.w * 32 + c]);
        float v4 = b2f(hwb[(size_t)e1.x * 32 + c]);
        float v5 = b2f(hwb[(size_t)e1.y * 32 + c]);
        float v6 = b2f(hwb[(size_t)e1.z * 32 + c]);
        float v7 = b2f(hwb[(size_t)e1.w * 32 + c]);
        acc0 += (v0 + v1) + (v2 + v3);
        acc1 += (v4 + v5) + (v6 + v7);
    }
    hs[nl][c] = fmaxf(fmaf(dn, acc0 + acc1, bias2[c]), 0.0f);
    __syncthreads();
    if (t < 128) {
        int nn = t >> 4, jj = t & 15;
        float s = B1[jj];
#pragma unroll
        for (int k = 0; k < 32; ++k) s += hs[nn][k] * W1[k * 16 + jj];
        float p = fmaxf(s, 0.0f) * W2[jj];
        p += __shfl_xor(p, 1);
        p += __shfl_xor(p, 2);
        p += __shfl_xor(p, 4);
        p += __shfl_xor(p, 8);
        if (jj == 0) out[node0 + nn] = p + bf2[0];
    }
}

// ---------------- host ----------------

extern "C" void kernel_launch(void* const* d_in, const int* in_sizes, int n_in,
                              void* d_out, int out_size, void* d_ws, size_t ws_size,
                              hipStream_t stream) {
    const float* x   = (const float*)d_in[0];
    const int*   ei  = (const int*)d_in[1];
    const float* w1  = (const float*)d_in[2];
    const float* b1  = (const float*)d_in[3];
    const float* w2  = (const float*)d_in[4];
    const float* b2  = (const float*)d_in[5];
    const float* wf1 = (const float*)d_in[6];
    const float* bf1 = (const float*)d_in[7];
    const float* wf2 = (const float*)d_in[8];
    const float* bf2 = (const float*)d_in[9];

    const int n = N_NODES;
    const int E = N_EDGES;
    const int* srcp = ei;        // edge_index[0]
    const int* dstp = ei + E;    // edge_index[1]

    char* p = (char*)d_ws;
    auto take = [&](size_t bytes) {
        char* r = p;
        p += (bytes + 255) & ~(size_t)255;
        return r;
    };
    float* dinv = (float*)take((size_t)n * 4);
    int*   cnt  = (int*)take((size_t)n * 4);
    int*   off  = (int*)take((size_t)n * 4);
    int*   gcnt = (int*)take((size_t)NSLOT * 4);
    int*   bsum = (int*)take(512);
    int*   es   = (int*)take((size_t)ES_CAP * 4);
    unsigned short* hwb1 = (unsigned short*)take((size_t)(n + 1) * 64 * 2);  // aliases ebuf
    unsigned short* hwb2 = (unsigned short*)take((size_t)(n + 1) * 32 * 2);
    float* h1   = (float*)take((size_t)n * 64 * 4);
    unsigned* ebuf = (unsigned*)hwb1;   // 6.4MB, consumed by k_bucket_csr before gemm1

    // build per-node padded CSR (bucketed two-phase, no global atomics)
    k_zero_sent<<<1, 96, 0, stream>>>(hwb1, hwb2);
    k_hist<<<NPB, 256, 0, stream>>>(dstp, gcnt, E);
    k_scanA<<<NSB, 1024, 0, stream>>>(gcnt, bsum, NSLOT);
    k_scanB<<<1, 128, 0, stream>>>(bsum, NSB);
    k_scanC<<<NSB, 1024, 0, stream>>>(gcnt, bsum, NSLOT);
    k_partition<<<NPB, 256, 0, stream>>>(srcp, dstp, gcnt, ebuf, E);
    k_bucket_csr<<<NBK, 256, 0, stream>>>(gcnt, ebuf, cnt, dinv, off, es, n);

    // GNN layers
    k_gemm1_mfma<<<(n + 63) / 64, 256, 0, stream>>>(x, w1, dinv, hwb1, n);
    k_agg1<<<(n * 64) / 256, 256, 0, stream>>>(hwb1, dinv, cnt, off, es, b1, h1);
    k_gemm2_mfma<<<(n + 63) / 64, 256, 0, stream>>>(h1, w2, dinv, hwb2, n);
    k_agg2_mlp<<<n / 8, 256, 0, stream>>>(hwb2, dinv, cnt, off, es, b2,
                                          wf1, bf1, wf2, bf2, (float*)d_out);
}